// Round 4
// baseline (293.894 us; speedup 1.0000x reference)
//
#include <hip/hip_runtime.h>
#include <hip/hip_bf16.h>
#include <stdint.h>

// Q_Mlp: HAWQ-style quantized MLP on MI355X (gfx950).
// B=256, S=196 -> M=50176 rows. D=384, H=1536.
// Exact-integer int8 GEMMs via v_mfma_i32_16x16x64_i8.
// Round 4: fragment-ordered LDS (conflict-free ds_read_b128 via pre-permuted
//          global_load_lds source), integer-max pass-A epilogue.

#define M_TOT 50176
#define D_IN  384
#define H_MID 1536
#define NSLOT 256

typedef int v4i __attribute__((ext_vector_type(4)));

__device__ __forceinline__ float clamp_q(float q) {
  return fminf(fmaxf(q, -128.0f), 127.0f);
}

__device__ __forceinline__ void gld_lds16(const int8_t* g, int8_t* s) {
  __builtin_amdgcn_global_load_lds((const __attribute__((address_space(1))) void*)g,
                                   (__attribute__((address_space(3))) void*)s,
                                   16, 0, 0);
}

// One wave per weight row: row-max -> w_sf, int8 quantize, optional b_int.
__global__ void quant_w_kernel(const float* __restrict__ W, const float* __restrict__ b,
                               int8_t* __restrict__ Wq, float* __restrict__ wsf,
                               int* __restrict__ bint, const float* __restrict__ asf_p,
                               int cols) {
  const int lane = threadIdx.x & 63;
  const int row  = blockIdx.x * 4 + (threadIdx.x >> 6);
  const float* wr = W + (size_t)row * cols;
  float m = 0.f;
  for (int c = lane; c < cols; c += 64) m = fmaxf(m, fabsf(wr[c]));
#pragma unroll
  for (int off = 32; off; off >>= 1) m = fmaxf(m, __shfl_xor(m, off));
  const float sf = m / 127.0f;              // matches jnp: max/QMAX (f32 division)
  int8_t* qr = Wq + (size_t)row * cols;
  for (int c = lane; c < cols; c += 64)
    qr[c] = (int8_t)clamp_q(rintf(wr[c] / sf));   // round-half-even, f32 division
  if (lane == 0) {
    wsf[row] = sf;
    if (bint) bint[row] = (int)rintf(b[row] / (sf * asf_p[0]));
  }
}

__global__ void quant_x_kernel(const float4* __restrict__ x, char4* __restrict__ xq,
                               const float* __restrict__ asf_p, int n4) {
  const float asf = asf_p[0];
  const int stride = gridDim.x * blockDim.x;
  for (int i = blockIdx.x * blockDim.x + threadIdx.x; i < n4; i += stride) {
    float4 v = x[i];
    char4 q;
    q.x = (signed char)clamp_q(rintf(v.x / asf));
    q.y = (signed char)clamp_q(rintf(v.y / asf));
    q.z = (signed char)clamp_q(rintf(v.z / asf));
    q.w = (signed char)clamp_q(rintf(v.w / asf));
    xq[i] = q;
  }
}

// C[m,n] = sum_k A[m,k]*B[n,k]  (both K-major int8), 128x128 tile, BK=64.
// LDS layout is FRAGMENT-ORDERED: byte p of a tile holds the value lane
// (p>>4)&63 of row-block p>>10 consumes -> ds_read_b128 is lane-consecutive
// (conflict-free). Achieved by permuting the per-thread GLOBAL source of the
// linear global_load_lds writes (rule 21: swizzle source + read, dest linear).
// MODE 0: GEMM1 max pass  — no store; integer col-max -> slot atomicMax.
// MODE 1: GEMM1 quant pass — store hq int8 on sf1 grid (exact f32 division).
// MODE 2: GEMM2           — store y_pre f32; slot atomicMax |y_pre|.
template <int MODE>
__global__ __launch_bounds__(256) void gemm_i8_kernel(
    const int8_t* __restrict__ A, const int8_t* __restrict__ Bm,
    int N, int K, int ntiles_n,
    const float* __restrict__ sfv, const int* __restrict__ bintv,
    const float* __restrict__ bias, const float* __restrict__ asf_p,
    const unsigned* __restrict__ gmax_in,   // NSLOT slots
    float* __restrict__ Cout, int8_t* __restrict__ Cq,
    unsigned* __restrict__ gmax_out) {      // NSLOT slots
  __shared__ __align__(16) int8_t sA[2][8192];
  __shared__ __align__(16) int8_t sB[2][8192];
  const int tid  = threadIdx.x;
  const int lane = tid & 63;
  const int wid  = tid >> 6;
  // bijective XCD swizzle (grids divisible by 8)
  const int cpx = gridDim.x >> 3;
  const int wg  = (blockIdx.x & 7) * cpx + (blockIdx.x >> 3);
  const int bn = wg % ntiles_n;
  const int bm = wg / ntiles_n;
  const int l16  = lane & 15;

  // fragment-ordered staging source: thread t fills LDS bytes [t*16, t*16+16)
  // (and +4096 for rows 64..127). Required source: row blk*16+(t&15),
  // col ((t>>4)&3)*16, blk = t>>6.
  const int f    = tid * 16;
  const int srow = (tid >> 6) * 16 + (tid & 15);
  const int scol = ((tid >> 4) & 3) * 16;
  const int8_t* gA0 = A  + ((size_t)(bm * 128 + srow)) * K + scol;
  const int8_t* gB0 = Bm + ((size_t)(bn * 128 + srow)) * K + scol;
  const size_t rstep = (size_t)64 * K;

  // fragment read bases: row-block (wm/16 + i) at lane*16
  const int wmblk = (wid >> 1) * 4;
  const int wnblk = (wid & 1) * 4;
  const int lbase = lane * 16;

  v4i acc[4][4] = {};
  const int kmax = K >> 6;

  // prologue: stage tile 0 into buf 0
  gld_lds16(gA0,         &sA[0][f]);
  gld_lds16(gA0 + rstep, &sA[0][4096 + f]);
  gld_lds16(gB0,         &sB[0][f]);
  gld_lds16(gB0 + rstep, &sB[0][4096 + f]);
  __syncthreads();

  for (int kt = 0; kt < kmax; ++kt) {
    const int cur = kt & 1;
    if (kt + 1 < kmax) {               // uniform branch: prefetch next K-tile
      const int kb = (kt + 1) << 6;
      gld_lds16(gA0 + kb,         &sA[cur ^ 1][f]);
      gld_lds16(gA0 + rstep + kb, &sA[cur ^ 1][4096 + f]);
      gld_lds16(gB0 + kb,         &sB[cur ^ 1][f]);
      gld_lds16(gB0 + rstep + kb, &sB[cur ^ 1][4096 + f]);
    }
    v4i va[4], vb[4];
#pragma unroll
    for (int i = 0; i < 4; ++i)
      va[i] = *(const v4i*)&sA[cur][(wmblk + i) * 1024 + lbase];
#pragma unroll
    for (int j = 0; j < 4; ++j)
      vb[j] = *(const v4i*)&sB[cur][(wnblk + j) * 1024 + lbase];
#pragma unroll
    for (int i = 0; i < 4; ++i)
#pragma unroll
      for (int j = 0; j < 4; ++j)
        acc[i][j] = __builtin_amdgcn_mfma_i32_16x16x64_i8(va[i], vb[j], acc[i][j], 0, 0, 0);
    __syncthreads();   // drains vmcnt (prefetch landed) + lgkmcnt; guards buf reuse
  }

  // sf1 for MODE 1/2: reduce slot array once per block (LDS free now)
  float sf1 = 0.f, asf = 0.f;
  if (MODE == 0) {
    asf = asf_p[0];
  } else {
    float* bcast = (float*)&sA[0][0];
    if (wid == 0) {
      float m = fmaxf(fmaxf(__uint_as_float(gmax_in[lane]),
                            __uint_as_float(gmax_in[lane + 64])),
                      fmaxf(__uint_as_float(gmax_in[lane + 128]),
                            __uint_as_float(gmax_in[lane + 192])));
#pragma unroll
      for (int off = 32; off; off >>= 1) m = fmaxf(m, __shfl_xor(m, off));
      if (lane == 0) *bcast = m / 127.0f;
    }
    __syncthreads();
    sf1 = *bcast;
    if (MODE == 1) asf = asf_p[0];
  }

  // epilogue: C/D layout col = lane&15, row = (lane>>4)*4 + reg
  const int wm = (wid >> 1) * 64;
  const int wn = (wid & 1) * 64;
  float lmax = 0.f;
  const int r0 = (lane >> 4) * 4;

  if (MODE == 0) {
    // max(relu(h)) per column = scale * max(acc) + bias folded (scale>0,
    // bi uniform per col) -> pure integer max tree, 4 f32 ops per column.
#pragma unroll
    for (int j = 0; j < 4; ++j) {
      int mi = acc[0][j][0];
#pragma unroll
      for (int i = 0; i < 4; ++i)
#pragma unroll
        for (int r = 0; r < 4; ++r) mi = max(mi, acc[i][j][r]);
      const int col = bn * 128 + wn + j * 16 + l16;
      const float v = (float)(mi + bintv[col]) * (sfv[col] * asf);
      lmax = fmaxf(lmax, v);   // lmax>=0 covers relu
    }
  } else {
#pragma unroll
    for (int j = 0; j < 4; ++j) {
      const int col = bn * 128 + wn + j * 16 + l16;
      float scale;
      int bi;
      if (MODE == 2) { scale = sfv[col] * sf1; bi = (int)rintf(bias[col] / scale); }
      else           { scale = sfv[col] * asf; bi = bintv[col]; }
#pragma unroll
      for (int i = 0; i < 4; ++i) {
        const int row = bm * 128 + wm + i * 16 + r0;
#pragma unroll
        for (int r = 0; r < 4; ++r) {
          float v = (float)(acc[i][j][r] + bi) * scale;  // exact int add, one f32 mul
          if (MODE == 1) {
            v = fmaxf(v, 0.f);                            // relu
            // exact f32 division required: rint boundary must match reference
            Cq[(size_t)(row + r) * N + col] = (int8_t)fminf(rintf(v / sf1), 127.0f);
          } else {
            lmax = fmaxf(lmax, fabsf(v));
            Cout[(size_t)(row + r) * N + col] = v;
          }
        }
      }
    }
  }
  if (MODE != 1) {
#pragma unroll
    for (int off = 32; off; off >>= 1) lmax = fmaxf(lmax, __shfl_xor(lmax, off));
    // one atomic per wave, spread over NSLOT slots (nonneg: uint order == float order)
    if (lane == 0) atomicMax(&gmax_out[(wg * 4 + wid) & (NSLOT - 1)], __float_as_uint(lmax));
  }
}

__global__ void final_quant_kernel(float* __restrict__ y, const unsigned* __restrict__ slots,
                                   int n4) {
  __shared__ float s_sf;
  const int tid = threadIdx.x;
  if (tid < 64) {
    float m = fmaxf(fmaxf(__uint_as_float(slots[tid]),
                          __uint_as_float(slots[tid + 64])),
                    fmaxf(__uint_as_float(slots[tid + 128]),
                          __uint_as_float(slots[tid + 192])));
#pragma unroll
    for (int off = 32; off; off >>= 1) m = fmaxf(m, __shfl_xor(m, off));
    if (tid == 0) s_sf = m / 127.0f;
  }
  __syncthreads();
  const float asf2 = s_sf;
  float4* y4 = (float4*)y;
  const int stride = gridDim.x * blockDim.x;
  for (int i = blockIdx.x * blockDim.x + tid; i < n4; i += stride) {
    float4 v = y4[i];
    v.x = clamp_q(rintf(v.x / asf2)) * asf2;
    v.y = clamp_q(rintf(v.y / asf2)) * asf2;
    v.z = clamp_q(rintf(v.z / asf2)) * asf2;
    v.w = clamp_q(rintf(v.w / asf2)) * asf2;
    y4[i] = v;
  }
  if (blockIdx.x == 0 && tid == 0) y[(size_t)n4 * 4] = asf2;  // output 1: asf2
}

extern "C" void kernel_launch(void* const* d_in, const int* in_sizes, int n_in,
                              void* d_out, int out_size, void* d_ws, size_t ws_size,
                              hipStream_t stream) {
  const float* x   = (const float*)d_in[0];
  const float* W1  = (const float*)d_in[1];
  const float* b1  = (const float*)d_in[2];
  const float* W2  = (const float*)d_in[3];
  const float* b2  = (const float*)d_in[4];
  const float* asf = (const float*)d_in[5];

  char* ws = (char*)d_ws;
  unsigned* gmax1 = (unsigned*)ws;           // NSLOT slots: max(relu(h))
  unsigned* gmax2 = (unsigned*)(ws + 1024);  // NSLOT slots: max|y_pre|
  size_t off = 4096;
  int8_t* xq   = (int8_t*)(ws + off); off += (size_t)M_TOT * D_IN;   // 19.3 MB
  int8_t* w1q  = (int8_t*)(ws + off); off += (size_t)H_MID * D_IN;   // 0.6 MB
  float*  w1sf = (float*)(ws + off);  off += (size_t)H_MID * 4;
  int*    b1i  = (int*)(ws + off);    off += (size_t)H_MID * 4;
  int8_t* w2q  = (int8_t*)(ws + off); off += (size_t)D_IN * H_MID;   // 0.6 MB
  float*  w2sf = (float*)(ws + off);  off += (size_t)D_IN * 4;
  off = (off + 255) & ~(size_t)255;
  int8_t* hq   = (int8_t*)(ws + off); off += (size_t)M_TOT * H_MID;  // 77.1 MB

  hipMemsetAsync(d_ws, 0, 4096, stream);  // zero both slot arrays every call

  quant_w_kernel<<<H_MID / 4, 256, 0, stream>>>(W1, b1, w1q, w1sf, b1i, asf, D_IN);
  quant_w_kernel<<<D_IN / 4, 256, 0, stream>>>(W2, nullptr, w2q, w2sf, nullptr, nullptr, H_MID);
  quant_x_kernel<<<2048, 256, 0, stream>>>((const float4*)x, (char4*)xq, asf,
                                           M_TOT * D_IN / 4);
  // GEMM1 pass A: global max(relu(h)) only (grid 4704 = 8*588)
  gemm_i8_kernel<0><<<(M_TOT / 128) * (H_MID / 128), 256, 0, stream>>>(
      xq, w1q, H_MID, D_IN, H_MID / 128, w1sf, b1i, nullptr, asf, nullptr,
      nullptr, nullptr, gmax1);
  // GEMM1 pass B: emit int8 hq on the sf1 grid
  gemm_i8_kernel<1><<<(M_TOT / 128) * (H_MID / 128), 256, 0, stream>>>(
      xq, w1q, H_MID, D_IN, H_MID / 128, w1sf, b1i, nullptr, asf, gmax1,
      nullptr, hq, nullptr);
  // GEMM2: y_pre into d_out + max|y_pre| (grid 1176 = 8*147)
  gemm_i8_kernel<2><<<(M_TOT / 128) * (D_IN / 128), 256, 0, stream>>>(
      hq, w2q, D_IN, H_MID, D_IN / 128, w2sf, nullptr, b2, nullptr, gmax1,
      (float*)d_out, nullptr, gmax2);
  final_quant_kernel<<<2048, 256, 0, stream>>>((float*)d_out, gmax2, M_TOT * D_IN / 4);
}

// Round 5
// 282.062 us; speedup vs baseline: 1.0420x; 1.0420x over previous
//
#include <hip/hip_runtime.h>
#include <hip/hip_bf16.h>
#include <stdint.h>

// Q_Mlp: HAWQ-style quantized MLP on MI355X (gfx950).
// B=256, S=196 -> M=50176 rows. D=384, H=1536.
// Exact-integer int8 GEMMs via v_mfma_i32_16x16x64_i8.
// Round 5: whole-K-chunk LDS panels (BM=128 x BN=64, K-chunk=384, one barrier
// per chunk), int8 operands stored in 16x16-TILED layout so every
// global_load_lds source is a contiguous 1KB per wave AND LDS lands in
// fragment order (conflict-free ds_read_b128). Final quantization folded
// into a GEMM2 max-pass + store-pass (no separate 154MB pass).

#define M_TOT 50176
#define D_IN  384
#define H_MID 1536
#define OUT_N (M_TOT * D_IN)
#define NSLOT 256

typedef int v4i __attribute__((ext_vector_type(4)));

__device__ __forceinline__ float clamp_q(float q) {
  return fminf(fmaxf(q, -128.0f), 127.0f);
}

__device__ __forceinline__ void gld_lds16(const int8_t* g, int8_t* s) {
  __builtin_amdgcn_global_load_lds((const __attribute__((address_space(1))) void*)g,
                                   (__attribute__((address_space(3))) void*)s,
                                   16, 0, 0);
}

// Tiled int8 layout: addr(row,k) = (row>>4)*16*K + (k>>4)*256 + (row&15)*16 + (k&15)

// One wave per weight row: row-max -> w_sf, tiled int8 quantize, optional b_int.
__global__ void quant_w_kernel(const float* __restrict__ W, const float* __restrict__ b,
                               int8_t* __restrict__ Wq, float* __restrict__ wsf,
                               int* __restrict__ bint, const float* __restrict__ asf_p,
                               int cols) {
  const int lane = threadIdx.x & 63;
  const int row  = blockIdx.x * 4 + (threadIdx.x >> 6);
  const float* wr = W + (size_t)row * cols;
  float m = 0.f;
  for (int c = lane; c < cols; c += 64) m = fmaxf(m, fabsf(wr[c]));
#pragma unroll
  for (int off = 32; off; off >>= 1) m = fmaxf(m, __shfl_xor(m, off));
  const float sf = m / 127.0f;              // matches jnp: max/QMAX (f32 division)
  int8_t* qbase = Wq + (size_t)(row >> 4) * 16 * cols + (row & 15) * 16;
  for (int c = lane; c < cols; c += 64)
    qbase[(c >> 4) * 256 + (c & 15)] = (int8_t)clamp_q(rintf(wr[c] / sf));
  if (lane == 0) {
    wsf[row] = sf;
    if (bint) bint[row] = (int)rintf(b[row] / (sf * asf_p[0]));
  }
}

// One wave-task = one (16-row panel, 4 k-chunks): lane handles 16 k of one row;
// writes one contiguous 1KB block of the tiled xq.
__global__ void quant_x_kernel(const float* __restrict__ x, int8_t* __restrict__ xq,
                               const float* __restrict__ asf_p) {
  const int lane = threadIdx.x & 63;
  const int wid  = threadIdx.x >> 6;
  const float asf = asf_p[0];
  const int r  = lane & 15;
  const int kq = lane >> 4;
  const int ntask = (M_TOT / 16) * 6;   // 3136 panels * 6 (k-chunk quads)
  for (int task = blockIdx.x * 4 + wid; task < ntask; task += gridDim.x * 4) {
    const int pan = task / 6;
    const int kcq = task - pan * 6;
    const float* src = x + ((size_t)pan * 16 + r) * D_IN + (kcq * 4 + kq) * 16;
    int out[4];
#pragma unroll
    for (int q4 = 0; q4 < 4; ++q4) {
      float4 v = *(const float4*)(src + q4 * 4);
      unsigned a0 = (unsigned char)(signed char)clamp_q(rintf(v.x / asf));
      unsigned a1 = (unsigned char)(signed char)clamp_q(rintf(v.y / asf));
      unsigned a2 = (unsigned char)(signed char)clamp_q(rintf(v.z / asf));
      unsigned a3 = (unsigned char)(signed char)clamp_q(rintf(v.w / asf));
      out[q4] = (int)(a0 | (a1 << 8) | (a2 << 16) | (a3 << 24));
    }
    *(int4*)(xq + (size_t)pan * 6144 + kcq * 1024 + lane * 16) = *(int4*)out;
  }
}

// GEMM: C[m,n] = sum_k A[m,k]*B[n,k], A/B in tiled-int8. Tile BM=128 x BN=64,
// K processed in resident chunks of 384 (48KB A + 24KB B in LDS, one barrier
// pair per chunk). 4 waves: wave tile 64x32 = acc[4][2] of 16x16 frags.
// MODE 0: GEMM1 max pass   — integer col-max -> slot atomicMax(max relu(h)).
// MODE 1: GEMM1 quant pass — store hq int8 (tiled, K=1536 stride) on sf1 grid.
// MODE 2: GEMM2 max pass   — integer col-max/min -> slot atomicMax(|y_pre|).
// MODE 3: GEMM2 store pass — y = clamp(rint(y_pre/asf2))*asf2 into d_out.
template <int MODE>
__global__ __launch_bounds__(256) void gemm_i8_kernel(
    const int8_t* __restrict__ A, const int8_t* __restrict__ Bm,
    int K, int nchunks, int ntiles_n,
    const float* __restrict__ sfv, const int* __restrict__ bintv,
    const float* __restrict__ bias, const float* __restrict__ asf_p,
    const unsigned* __restrict__ gmax_in, const unsigned* __restrict__ gmax_in2,
    float* __restrict__ Cout, int8_t* __restrict__ Cq,
    unsigned* __restrict__ gmax_out) {
  __shared__ __align__(16) int8_t sA[49152];   // 8 row-blocks x 6 kc x 1KB frag
  __shared__ __align__(16) int8_t sB[24576];   // 4 row-blocks x 6 kc x 1KB frag
  __shared__ float bcastv[2];
  const int tid   = threadIdx.x;
  const int lane  = tid & 63;
  const int wid   = tid >> 6;
  const int tid16 = tid * 16;
  const int lane16 = lane * 16;
  // bijective XCD swizzle (grids divisible by 8)
  const int cpx = gridDim.x >> 3;
  const int wg  = (blockIdx.x & 7) * cpx + (blockIdx.x >> 3);
  const int bn = wg % ntiles_n;
  const int bm = wg / ntiles_n;
  const int l16 = lane & 15;

  // scale broadcast (sf1 / asf2) — written by wave 0 before the first barrier
  if (MODE != 0 && wid == 0) {
    float m = fmaxf(fmaxf(__uint_as_float(gmax_in[lane]),
                          __uint_as_float(gmax_in[lane + 64])),
                    fmaxf(__uint_as_float(gmax_in[lane + 128]),
                          __uint_as_float(gmax_in[lane + 192])));
#pragma unroll
    for (int off = 32; off; off >>= 1) m = fmaxf(m, __shfl_xor(m, off));
    if (lane == 0) bcastv[0] = m / 127.0f;
    if (MODE == 3) {
      float m2 = fmaxf(fmaxf(__uint_as_float(gmax_in2[lane]),
                             __uint_as_float(gmax_in2[lane + 64])),
                       fmaxf(__uint_as_float(gmax_in2[lane + 128]),
                             __uint_as_float(gmax_in2[lane + 192])));
#pragma unroll
      for (int off = 32; off; off >>= 1) m2 = fmaxf(m2, __shfl_xor(m2, off));
      if (lane == 0) bcastv[1] = m2 / 127.0f;
    }
  }

  // staging offsets: load l fills LDS frag idx = l*4 + wid (1KB contiguous per
  // wave, src contiguous 1KB in tiled global layout)
  const int8_t* gA0 = A  + (size_t)(bm * 128) * K;
  const int8_t* gB0 = Bm + (size_t)(bn * 64) * K;
  int aoff[12], boff[6];
#pragma unroll
  for (int l = 0; l < 12; ++l) {
    const unsigned idx = l * 4 + wid;
    const unsigned ab = idx / 6u, kc = idx - 6u * ab;
    aoff[l] = (int)(ab * 16u * (unsigned)K + kc * 1024u) + lane16;
  }
#pragma unroll
  for (int l = 0; l < 6; ++l) {
    const unsigned idx = l * 4 + wid;
    const unsigned bb = idx / 6u, kc = idx - 6u * bb;
    boff[l] = (int)(bb * 16u * (unsigned)K + kc * 1024u) + lane16;
  }

  const int wmblk = (wid >> 1) * 4;   // A row-block base (of 8)
  const int wnblk = (wid & 1) * 2;    // B row-block base (of 4)

  v4i acc[4][2] = {};

  for (int c = 0; c < nchunks; ++c) {
    const int cb = c * 6144;          // (384/16)*256 bytes per k-chunk advance
#pragma unroll
    for (int l = 0; l < 12; ++l) gld_lds16(gA0 + aoff[l] + cb, sA + l * 4096 + tid16);
#pragma unroll
    for (int l = 0; l < 6; ++l)  gld_lds16(gB0 + boff[l] + cb, sB + l * 4096 + tid16);
    __syncthreads();                  // vmcnt(0) drain: panels resident
#pragma unroll
    for (int kc = 0; kc < 6; ++kc) {
      v4i va[4], vb[2];
#pragma unroll
      for (int i = 0; i < 4; ++i)
        va[i] = *(const v4i*)&sA[((wmblk + i) * 6 + kc) * 1024 + lane16];
#pragma unroll
      for (int j = 0; j < 2; ++j)
        vb[j] = *(const v4i*)&sB[((wnblk + j) * 6 + kc) * 1024 + lane16];
#pragma unroll
      for (int i = 0; i < 4; ++i)
#pragma unroll
        for (int j = 0; j < 2; ++j)
          acc[i][j] = __builtin_amdgcn_mfma_i32_16x16x64_i8(va[i], vb[j], acc[i][j], 0, 0, 0);
    }
    __syncthreads();                  // all reads done before next chunk overwrites
  }

  // epilogue: C/D frag layout col = lane&15, row = (lane>>4)*4 + reg
  const int wm = (wid >> 1) * 64;
  const int wn = (wid & 1) * 32;
  const int r0 = (lane >> 4) * 4;
  float lmax = 0.f;

  if (MODE == 0) {
#pragma unroll
    for (int j = 0; j < 2; ++j) {
      int mi = acc[0][j][0];
#pragma unroll
      for (int i = 0; i < 4; ++i)
#pragma unroll
        for (int r = 0; r < 4; ++r) mi = max(mi, acc[i][j][r]);
      const int col = bn * 64 + wn + j * 16 + l16;
      lmax = fmaxf(lmax, (float)(mi + bintv[col]) * (sfv[col] * asf_p[0]));
    }
  } else if (MODE == 1) {
    const float sf1 = bcastv[0];
    const float asf = asf_p[0];
#pragma unroll
    for (int j = 0; j < 2; ++j) {
      const int col = bn * 64 + wn + j * 16 + l16;
      const float scale = sfv[col] * asf;
      const int bi = bintv[col];
      const size_t cc = (size_t)((bn * 4 + (wid & 1) * 2 + j) << 8);
#pragma unroll
      for (int i = 0; i < 4; ++i) {
        const size_t prow = (size_t)(bm * 8 + (wid >> 1) * 4 + i) * (16 * H_MID);
#pragma unroll
        for (int r = 0; r < 4; ++r) {
          float v = fmaxf((float)(acc[i][j][r] + bi) * scale, 0.f);  // relu
          // exact f32 division: rint boundary must match reference
          Cq[prow + cc + (size_t)((r0 + r) * 16 + l16)] =
              (int8_t)fminf(rintf(v / sf1), 127.0f);
        }
      }
    }
  } else if (MODE == 2) {
    const float sf1 = bcastv[0];
#pragma unroll
    for (int j = 0; j < 2; ++j) {
      int mi = acc[0][j][0], mn = acc[0][j][0];
#pragma unroll
      for (int i = 0; i < 4; ++i)
#pragma unroll
        for (int r = 0; r < 4; ++r) { mi = max(mi, acc[i][j][r]); mn = min(mn, acc[i][j][r]); }
      const int col = bn * 64 + wn + j * 16 + l16;
      const float scale = sfv[col] * sf1;
      const int bi = (int)rintf(bias[col] / scale);
      lmax = fmaxf(lmax, fmaxf(fabsf((float)(mi + bi) * scale),
                               fabsf((float)(mn + bi) * scale)));
    }
  } else {  // MODE 3
    const float sf1  = bcastv[0];
    const float asf2 = bcastv[1];
#pragma unroll
    for (int j = 0; j < 2; ++j) {
      const int col = bn * 64 + wn + j * 16 + l16;
      const float scale = sfv[col] * sf1;
      const int bi = (int)rintf(bias[col] / scale);
#pragma unroll
      for (int i = 0; i < 4; ++i) {
        const int row = bm * 128 + wm + i * 16 + r0;
#pragma unroll
        for (int r = 0; r < 4; ++r) {
          const float v = (float)(acc[i][j][r] + bi) * scale;
          Cout[(size_t)(row + r) * D_IN + col] = clamp_q(rintf(v / asf2)) * asf2;
        }
      }
    }
    if (blockIdx.x == 0 && tid == 0) Cout[OUT_N] = asf2;   // output 1: asf2
  }

  if (MODE == 0 || MODE == 2) {
#pragma unroll
    for (int off = 32; off; off >>= 1) lmax = fmaxf(lmax, __shfl_xor(lmax, off));
    // one atomic per wave, spread over NSLOT slots (nonneg: uint order == float order)
    if (lane == 0) atomicMax(&gmax_out[(wg * 4 + wid) & (NSLOT - 1)], __float_as_uint(lmax));
  }
}

extern "C" void kernel_launch(void* const* d_in, const int* in_sizes, int n_in,
                              void* d_out, int out_size, void* d_ws, size_t ws_size,
                              hipStream_t stream) {
  const float* x   = (const float*)d_in[0];
  const float* W1  = (const float*)d_in[1];
  const float* b1  = (const float*)d_in[2];
  const float* W2  = (const float*)d_in[3];
  const float* b2  = (const float*)d_in[4];
  const float* asf = (const float*)d_in[5];

  char* ws = (char*)d_ws;
  unsigned* gmax1 = (unsigned*)ws;           // NSLOT slots: max(relu(h))
  unsigned* gmax2 = (unsigned*)(ws + 1024);  // NSLOT slots: max|y_pre|
  size_t off = 4096;
  int8_t* xq   = (int8_t*)(ws + off); off += (size_t)M_TOT * D_IN;   // 19.3 MB (tiled)
  int8_t* w1q  = (int8_t*)(ws + off); off += (size_t)H_MID * D_IN;   // 0.6 MB (tiled)
  float*  w1sf = (float*)(ws + off);  off += (size_t)H_MID * 4;
  int*    b1i  = (int*)(ws + off);    off += (size_t)H_MID * 4;
  int8_t* w2q  = (int8_t*)(ws + off); off += (size_t)D_IN * H_MID;   // 0.6 MB (tiled)
  float*  w2sf = (float*)(ws + off);  off += (size_t)D_IN * 4;
  off = (off + 255) & ~(size_t)255;
  int8_t* hq   = (int8_t*)(ws + off); off += (size_t)M_TOT * H_MID;  // 77.1 MB (tiled)

  hipMemsetAsync(d_ws, 0, 4096, stream);  // zero both slot arrays every call

  quant_w_kernel<<<H_MID / 4, 256, 0, stream>>>(W1, b1, w1q, w1sf, b1i, asf, D_IN);
  quant_w_kernel<<<D_IN / 4, 256, 0, stream>>>(W2, nullptr, w2q, w2sf, nullptr, nullptr, H_MID);
  quant_x_kernel<<<2048, 256, 0, stream>>>(x, xq, asf);

  const int g1 = (M_TOT / 128) * (H_MID / 64);  // 392*24 = 9408 (div by 8)
  const int g2 = (M_TOT / 128) * (D_IN / 64);   // 392*6  = 2352 (div by 8)
  // GEMM1 pass A: max(relu(h)) only
  gemm_i8_kernel<0><<<g1, 256, 0, stream>>>(
      xq, w1q, D_IN, 1, H_MID / 64, w1sf, b1i, nullptr, asf,
      nullptr, nullptr, nullptr, nullptr, gmax1);
  // GEMM1 pass B: emit tiled int8 hq on the sf1 grid
  gemm_i8_kernel<1><<<g1, 256, 0, stream>>>(
      xq, w1q, D_IN, 1, H_MID / 64, w1sf, b1i, nullptr, asf,
      gmax1, nullptr, nullptr, hq, nullptr);
  // GEMM2 pass A: max|y_pre| only
  gemm_i8_kernel<2><<<g2, 256, 0, stream>>>(
      hq, w2q, H_MID, 4, D_IN / 64, w2sf, nullptr, b2, nullptr,
      gmax1, nullptr, nullptr, nullptr, gmax2);
  // GEMM2 pass B: final quantized y into d_out (+ asf2 scalar)
  gemm_i8_kernel<3><<<g2, 256, 0, stream>>>(
      hq, w2q, H_MID, 4, D_IN / 64, w2sf, nullptr, b2, nullptr,
      gmax1, gmax2, (float*)d_out, nullptr, nullptr);
}

// Round 6
// 215.282 us; speedup vs baseline: 1.3652x; 1.3102x over previous
//
#include <hip/hip_runtime.h>
#include <hip/hip_bf16.h>
#include <stdint.h>

// Q_Mlp: HAWQ-style quantized MLP on MI355X (gfx950).
// B=256, S=196 -> M=50176 rows. D=384, H=1536.
// Exact-integer int8 GEMMs via v_mfma_i32_16x16x64_i8, tiled int8 operands
// (16x16 tiles) so staging is contiguous-1KB-per-wave and LDS lands in
// fragment order (conflict-free ds_read_b128).
// Round 6: K-chunk 192 (36KB LDS -> 4 blocks/CU), Newton-div epilogues,
// GEMM2 stores y_pre into d_out + elementwise final quant (MODE3 GEMM dropped).

#define M_TOT 50176
#define D_IN  384
#define H_MID 1536
#define OUT_N (M_TOT * D_IN)
#define NSLOT 256

typedef int v4i __attribute__((ext_vector_type(4)));

__device__ __forceinline__ float clamp_q(float q) {
  return fminf(fmaxf(q, -128.0f), 127.0f);
}

// near-correctly-rounded t/d given R = 1/d (IEEE): ~1 ulp. Used only where
// rint-boundary flips are provably within the error budget.
__device__ __forceinline__ float fast_div(float t, float d, float R) {
  const float q1 = t * R;
  const float r  = fmaf(-d, q1, t);
  return fmaf(r, R, q1);
}

__device__ __forceinline__ void gld_lds16(const int8_t* g, int8_t* s) {
  __builtin_amdgcn_global_load_lds((const __attribute__((address_space(1))) void*)g,
                                   (__attribute__((address_space(3))) void*)s,
                                   16, 0, 0);
}

// Tiled int8 layout: addr(row,k) = (row>>4)*16*K + (k>>4)*256 + (row&15)*16 + (k&15)

// One wave per weight row: row-max -> w_sf, tiled int8 quantize, optional b_int.
// Small tensors: keep IEEE divisions (bit-exact quantization grid).
__global__ void quant_w_kernel(const float* __restrict__ W, const float* __restrict__ b,
                               int8_t* __restrict__ Wq, float* __restrict__ wsf,
                               int* __restrict__ bint, const float* __restrict__ asf_p,
                               int cols) {
  const int lane = threadIdx.x & 63;
  const int row  = blockIdx.x * 4 + (threadIdx.x >> 6);
  const float* wr = W + (size_t)row * cols;
  float m = 0.f;
  for (int c = lane; c < cols; c += 64) m = fmaxf(m, fabsf(wr[c]));
#pragma unroll
  for (int off = 32; off; off >>= 1) m = fmaxf(m, __shfl_xor(m, off));
  const float sf = m / 127.0f;              // matches jnp: max/QMAX (f32 division)
  int8_t* qbase = Wq + (size_t)(row >> 4) * 16 * cols + (row & 15) * 16;
  for (int c = lane; c < cols; c += 64)
    qbase[(c >> 4) * 256 + (c & 15)] = (int8_t)clamp_q(rintf(wr[c] / sf));
  if (lane == 0) {
    wsf[row] = sf;
    if (bint) bint[row] = (int)rintf(b[row] / (sf * asf_p[0]));
  }
}

// x is fake-quantized on the asf grid -> x*R rounds to the exact integer
// (|q|<=128, |err| <= 128*2^-23 << 0.5), so rintf(x*R) == rintf(x/asf) always.
__global__ void quant_x_kernel(const float* __restrict__ x, int8_t* __restrict__ xq,
                               const float* __restrict__ asf_p) {
  const int lane = threadIdx.x & 63;
  const int wid  = threadIdx.x >> 6;
  const float R = 1.0f / asf_p[0];
  const int r  = lane & 15;
  const int kq = lane >> 4;
  const int ntask = (M_TOT / 16) * 6;   // 3136 panels * 6 k-chunk quads
  for (int task = blockIdx.x * 4 + wid; task < ntask; task += gridDim.x * 4) {
    const int pan = task / 6;
    const int kcq = task - pan * 6;
    const float* src = x + ((size_t)pan * 16 + r) * D_IN + (kcq * 4 + kq) * 16;
    int out[4];
#pragma unroll
    for (int q4 = 0; q4 < 4; ++q4) {
      float4 v = *(const float4*)(src + q4 * 4);
      unsigned a0 = (unsigned char)(signed char)clamp_q(rintf(v.x * R));
      unsigned a1 = (unsigned char)(signed char)clamp_q(rintf(v.y * R));
      unsigned a2 = (unsigned char)(signed char)clamp_q(rintf(v.z * R));
      unsigned a3 = (unsigned char)(signed char)clamp_q(rintf(v.w * R));
      out[q4] = (int)(a0 | (a1 << 8) | (a2 << 16) | (a3 << 24));
    }
    *(int4*)(xq + (size_t)pan * 6144 + kcq * 1024 + lane * 16) = *(int4*)out;
  }
}

// GEMM: C[m,n] = sum_k A[m,k]*B[n,k], tiled-int8. BM=128 x BN=64, K-chunk=192
// (24KB A + 12KB B in LDS, one barrier pair per chunk, 4 blocks/CU).
// 4 waves: wave tile 64x32 = acc[4][2] of 16x16 frags.
// MODE 0: GEMM1 max pass   — integer col-max -> slot atomicMax(max relu(h)).
// MODE 1: GEMM1 quant pass — store hq int8 (tiled) on sf1 grid, Newton-div.
// MODE 2: GEMM2 store pass — y_pre f32 into Cout row-major + slot atomicMax |.|.
template <int MODE>
__global__ __launch_bounds__(256, 4) void gemm_i8_kernel(
    const int8_t* __restrict__ A, const int8_t* __restrict__ Bm,
    int K, int nchunks, int ntiles_n,
    const float* __restrict__ sfv, const int* __restrict__ bintv,
    const float* __restrict__ bias, const float* __restrict__ asf_p,
    const unsigned* __restrict__ gmax_in,
    float* __restrict__ Cout, int8_t* __restrict__ Cq,
    unsigned* __restrict__ gmax_out) {
  __shared__ __align__(16) int8_t sA[24576];   // 8 rowblk x 12 kc x 256B
  __shared__ __align__(16) int8_t sB[12288];   // 4 rowblk x 12 kc x 256B
  __shared__ float bcastv[4];
  const int tid    = threadIdx.x;
  const int lane   = tid & 63;
  const int wid    = tid >> 6;
  const int tid16  = tid * 16;
  const int lane16 = lane * 16;
  // bijective XCD swizzle (grids divisible by 8)
  const int cpx = gridDim.x >> 3;
  const int wg  = (blockIdx.x & 7) * cpx + (blockIdx.x >> 3);
  const int bn = wg % ntiles_n;
  const int bm = wg / ntiles_n;
  const int l16 = lane & 15;

  // sf1 broadcast — written by wave 0 before the first barrier
  if (MODE != 0 && wid == 0) {
    float m = fmaxf(fmaxf(__uint_as_float(gmax_in[lane]),
                          __uint_as_float(gmax_in[lane + 64])),
                    fmaxf(__uint_as_float(gmax_in[lane + 128]),
                          __uint_as_float(gmax_in[lane + 192])));
#pragma unroll
    for (int off = 32; off; off >>= 1) m = fmaxf(m, __shfl_xor(m, off));
    if (lane == 0) bcastv[0] = m / 127.0f;
  }

  // staging: load l fills LDS bytes [l*4096 + tid*16 ...); source = matching
  // fragment-order offset in the tiled global layout (contiguous 1KB per wave).
  const int8_t* gA0 = A  + (size_t)(bm * 128) * K;
  const int8_t* gB0 = Bm + (size_t)(bn * 64) * K;
  int aoff[6], boff[3];
#pragma unroll
  for (int l = 0; l < 6; ++l) {
    const int s = l * 256 + tid;
    const int rb = s / 192, rem = s - rb * 192;
    aoff[l] = rb * 16 * K + (rem >> 4) * 256 + (rem & 15) * 16;
  }
#pragma unroll
  for (int l = 0; l < 3; ++l) {
    const int s = l * 256 + tid;
    const int rb = s / 192, rem = s - rb * 192;
    boff[l] = rb * 16 * K + (rem >> 4) * 256 + (rem & 15) * 16;
  }

  const int wmblk = (wid >> 1) * 4;   // A row-block base (of 8)
  const int wnblk = (wid & 1) * 2;    // B row-block base (of 4)

  v4i acc[4][2] = {};

  for (int c = 0; c < nchunks; ++c) {
    const int cb = c * 3072;          // 12 k-chunks x 256B per chunk advance
#pragma unroll
    for (int l = 0; l < 6; ++l) gld_lds16(gA0 + aoff[l] + cb, sA + l * 4096 + tid16);
#pragma unroll
    for (int l = 0; l < 3; ++l) gld_lds16(gB0 + boff[l] + cb, sB + l * 4096 + tid16);
    __syncthreads();                  // vmcnt(0) drain: chunk resident
#pragma unroll
    for (int ks = 0; ks < 3; ++ks) {
      v4i va[4], vb[2];
#pragma unroll
      for (int i = 0; i < 4; ++i)
        va[i] = *(const v4i*)&sA[(wmblk + i) * 3072 + ks * 1024 + lane16];
#pragma unroll
      for (int j = 0; j < 2; ++j)
        vb[j] = *(const v4i*)&sB[(wnblk + j) * 3072 + ks * 1024 + lane16];
#pragma unroll
      for (int i = 0; i < 4; ++i)
#pragma unroll
        for (int j = 0; j < 2; ++j)
          acc[i][j] = __builtin_amdgcn_mfma_i32_16x16x64_i8(va[i], vb[j], acc[i][j], 0, 0, 0);
    }
    __syncthreads();                  // reads done before next chunk overwrites
  }

  // epilogue: C/D frag layout col = lane&15, row = (lane>>4)*4 + reg
  const int wm = (wid >> 1) * 64;
  const int wn = (wid & 1) * 32;
  const int r0 = (lane >> 4) * 4;
  float lmax = 0.f;

  if (MODE == 0) {
    // max(relu(h)) per column: monotone in acc (scale>0), relu via lmax>=0.
#pragma unroll
    for (int j = 0; j < 2; ++j) {
      int mi = acc[0][j][0];
#pragma unroll
      for (int i = 0; i < 4; ++i)
#pragma unroll
        for (int r = 0; r < 4; ++r) mi = max(mi, acc[i][j][r]);
      const int col = bn * 64 + wn + j * 16 + l16;
      lmax = fmaxf(lmax, (float)(mi + bintv[col]) * (sfv[col] * asf_p[0]));
    }
  } else if (MODE == 1) {
    const float sf1 = bcastv[0];
    const float R   = 1.0f / sf1;     // one IEEE div per thread
    const float asf = asf_p[0];
#pragma unroll
    for (int j = 0; j < 2; ++j) {
      const int col = bn * 64 + wn + j * 16 + l16;
      const float scale = sfv[col] * asf;
      const int bi = bintv[col];
      const size_t cc = (size_t)((bn * 4 + (wid & 1) * 2 + j) << 8);
#pragma unroll
      for (int i = 0; i < 4; ++i) {
        const size_t prow = (size_t)(bm * 8 + (wid >> 1) * 4 + i) * (16 * H_MID);
#pragma unroll
        for (int r = 0; r < 4; ++r) {
          const float t = fmaxf((float)(acc[i][j][r] + bi) * scale, 0.f);  // relu
          const float q = fminf(rintf(fast_div(t, sf1, R)), 127.0f);
          Cq[prow + cc + (size_t)((r0 + r) * 16 + l16)] = (int8_t)q;
        }
      }
    }
  } else {  // MODE 2: y_pre into Cout (row-major), |max| via integer extremes
    const float sf1 = bcastv[0];
#pragma unroll
    for (int j = 0; j < 2; ++j) {
      const int col = bn * 64 + wn + j * 16 + l16;
      const float scale = sfv[col] * sf1;
      const int bi = (int)rintf(bias[col] / scale);   // per-column, IEEE
      int mi = acc[0][j][0], mn = acc[0][j][0];
#pragma unroll
      for (int i = 0; i < 4; ++i) {
        const int row = bm * 128 + wm + i * 16 + r0;
#pragma unroll
        for (int r = 0; r < 4; ++r) {
          const int a = acc[i][j][r];
          mi = max(mi, a); mn = min(mn, a);
          Cout[(size_t)(row + r) * D_IN + col] = (float)(a + bi) * scale;
        }
      }
      lmax = fmaxf(lmax, fmaxf(fabsf((float)(mi + bi) * scale),
                               fabsf((float)(mn + bi) * scale)));
    }
  }

  if (MODE != 1) {
#pragma unroll
    for (int off = 32; off; off >>= 1) lmax = fmaxf(lmax, __shfl_xor(lmax, off));
    // one atomic per wave, spread over NSLOT slots (nonneg: uint order == float order)
    if (lane == 0) atomicMax(&gmax_out[(wg * 4 + wid) & (NSLOT - 1)], __float_as_uint(lmax));
  }
}

// In-place final per-tensor quantization of d_out (y_pre -> y), + asf2 scalar.
__global__ void final_quant_kernel(float* __restrict__ y, const unsigned* __restrict__ slots,
                                   int n4) {
  __shared__ float s_sf;
  const int tid = threadIdx.x;
  if (tid < 64) {
    float m = fmaxf(fmaxf(__uint_as_float(slots[tid]),
                          __uint_as_float(slots[tid + 64])),
                    fmaxf(__uint_as_float(slots[tid + 128]),
                          __uint_as_float(slots[tid + 192])));
#pragma unroll
    for (int off = 32; off; off >>= 1) m = fmaxf(m, __shfl_xor(m, off));
    if (tid == 0) s_sf = m / 127.0f;
  }
  __syncthreads();
  const float asf2 = s_sf;
  const float R = 1.0f / asf2;
  float4* y4 = (float4*)y;
  const int stride = gridDim.x * blockDim.x;
  for (int i = blockIdx.x * blockDim.x + tid; i < n4; i += stride) {
    float4 v = y4[i];
    v.x = clamp_q(rintf(fast_div(v.x, asf2, R))) * asf2;
    v.y = clamp_q(rintf(fast_div(v.y, asf2, R))) * asf2;
    v.z = clamp_q(rintf(fast_div(v.z, asf2, R))) * asf2;
    v.w = clamp_q(rintf(fast_div(v.w, asf2, R))) * asf2;
    y4[i] = v;
  }
  if (blockIdx.x == 0 && tid == 0) y[(size_t)n4 * 4] = asf2;  // output 1: asf2
}

extern "C" void kernel_launch(void* const* d_in, const int* in_sizes, int n_in,
                              void* d_out, int out_size, void* d_ws, size_t ws_size,
                              hipStream_t stream) {
  const float* x   = (const float*)d_in[0];
  const float* W1  = (const float*)d_in[1];
  const float* b1  = (const float*)d_in[2];
  const float* W2  = (const float*)d_in[3];
  const float* b2  = (const float*)d_in[4];
  const float* asf = (const float*)d_in[5];

  char* ws = (char*)d_ws;
  unsigned* gmax1 = (unsigned*)ws;           // NSLOT slots: max(relu(h))
  unsigned* gmax2 = (unsigned*)(ws + 1024);  // NSLOT slots: max|y_pre|
  size_t off = 4096;
  int8_t* xq   = (int8_t*)(ws + off); off += (size_t)M_TOT * D_IN;   // 19.3 MB (tiled)
  int8_t* w1q  = (int8_t*)(ws + off); off += (size_t)H_MID * D_IN;   // 0.6 MB (tiled)
  float*  w1sf = (float*)(ws + off);  off += (size_t)H_MID * 4;
  int*    b1i  = (int*)(ws + off);    off += (size_t)H_MID * 4;
  int8_t* w2q  = (int8_t*)(ws + off); off += (size_t)D_IN * H_MID;   // 0.6 MB (tiled)
  float*  w2sf = (float*)(ws + off);  off += (size_t)D_IN * 4;
  off = (off + 255) & ~(size_t)255;
  int8_t* hq   = (int8_t*)(ws + off); off += (size_t)M_TOT * H_MID;  // 77.1 MB (tiled)

  hipMemsetAsync(d_ws, 0, 4096, stream);  // zero both slot arrays every call

  quant_w_kernel<<<H_MID / 4, 256, 0, stream>>>(W1, b1, w1q, w1sf, b1i, asf, D_IN);
  quant_w_kernel<<<D_IN / 4, 256, 0, stream>>>(W2, nullptr, w2q, w2sf, nullptr, nullptr, H_MID);
  quant_x_kernel<<<2048, 256, 0, stream>>>(x, xq, asf);

  const int g1 = (M_TOT / 128) * (H_MID / 64);  // 392*24 = 9408 (div by 8)
  const int g2 = (M_TOT / 128) * (D_IN / 64);   // 392*6  = 2352 (div by 8)
  // GEMM1 pass A: max(relu(h)) only
  gemm_i8_kernel<0><<<g1, 256, 0, stream>>>(
      xq, w1q, D_IN, 2, H_MID / 64, w1sf, b1i, nullptr, asf,
      nullptr, nullptr, nullptr, gmax1);
  // GEMM1 pass B: emit tiled int8 hq on the sf1 grid
  gemm_i8_kernel<1><<<g1, 256, 0, stream>>>(
      xq, w1q, D_IN, 2, H_MID / 64, w1sf, b1i, nullptr, asf,
      gmax1, nullptr, hq, nullptr);
  // GEMM2: y_pre into d_out + slot max|y_pre|
  gemm_i8_kernel<2><<<g2, 256, 0, stream>>>(
      hq, w2q, H_MID, 8, D_IN / 64, w2sf, nullptr, b2, nullptr,
      gmax1, (float*)d_out, nullptr, gmax2);
  // final per-tensor quantization in place (+ asf2 scalar)
  final_quant_kernel<<<2048, 256, 0, stream>>>((float*)d_out, gmax2, OUT_N / 4);
}